// Round 4
// baseline (10718.391 us; speedup 1.0000x reference)
//
#include <hip/hip_runtime.h>
#include <cstdint>

#define B_SZ 8192
#define T_SZ 2048

// ---- model constants ----
#define C_LTS       0.126f
#define C_LMIN      (0.5f * 0.089f)
#define C_LMAX      (1.6f * 0.089f)
#define C_KT        35.0f
#define C_CT        0.2f
#define C_VMAX_L0   (10.0f * 0.089f)
#define C_AF_INV    4.0f
#define C_FAT_RATE  0.01f
#define C_REC_RATE  0.002f
#define C_TAU_ACT   0.01f
#define C_TAU_DEACT 0.04f
#define C_L0SIN     0.0077598346f          // L0 * sin(0.0873)
#define C_LMT_DEF   0.2146610680f          // LTS + L0*cos(0.0873)
#define C_INV_EM5   0.006783655f           // 1/(e^5 - 1)
#define C_INV_LTS   (1.0f / 0.126f)
#define C_INV_L0    (1.0f / 0.089f)
#define C_NN_SCALE  0.02f                  // (1-PHYSICS_WEIGHT) * 0.1

typedef __attribute__((ext_vector_type(8))) short bf16x8;
typedef __attribute__((ext_vector_type(4))) float f32x4;

__device__ __forceinline__ float fast_rcp(float x) { return __builtin_amdgcn_rcpf(x); }
__device__ __forceinline__ float fast_rsq(float x) { return __builtin_amdgcn_rsqf(x); }
__device__ __forceinline__ float fast_tanh(float x) {
    const float e2 = __expf(2.0f * x);
    return 1.0f - 2.0f * fast_rcp(e2 + 1.0f);
}
__device__ __forceinline__ float clampf(float x, float lo, float hi) {
    return fminf(fmaxf(x, lo), hi);
}
__device__ __forceinline__ short f2bf_trunc(float f) {
    return (short)(__float_as_uint(f) >> 16);
}
__device__ __forceinline__ short f2bf_rne(float f) {
    uint32_t u = __float_as_uint(f);
    u += 0x7fff + ((u >> 16) & 1);
    return (short)(u >> 16);
}
__device__ __forceinline__ float bf2f(short s) {
    return __uint_as_float(((uint32_t)(unsigned short)s) << 16);
}

// 8 waves (512 threads) per block cooperating on 16 elements — K-SPLIT:
// wave w: wv = w&3 (16-col tile), kh = w>>2 (K-half of the 64-unit sum).
// Per wave per stage: layer1 = 2 units/lane, 3 MFMAs (its K-half, hi/lo chain
// order identical to the 4-wave version -> bit-identical partial sums),
// float2 pacc exchange with the partner K-half wave, 2 h2 rows (tanh + W3
// partials), q-reduce, psum write (8 partials). Wave 0 runs the serial tail
// (psum tree -> nn -> physics -> RK4) and publishes cs; everyone re-reads cs.
// 4 barriers/stage: h1, pacc, psum, cs.
// Rationale: grid is pinned at 512 blocks; 4-wave blocks cap at 2 waves/SIMD
// (48% VALUBusy, 52% convoy stall). 8-wave blocks double TLP to 4 waves/SIMD.
__global__ __launch_bounds__(512) void ode_kernel(
    const float* __restrict__ init_state,   // (B,3)
    const float* __restrict__ exc,          // (B,T)
    const float* __restrict__ tspan,        // (T,)
    const float* __restrict__ W1,           // (4,64)
    const float* __restrict__ b1,           // (64,)
    const float* __restrict__ W2,           // (64,64)
    const float* __restrict__ b2,           // (64,)
    const float* __restrict__ W3,           // (64,3)
    const float* __restrict__ b3,           // (3,)
    float* __restrict__ out)                // (T,B,3)
{
    const int tid  = threadIdx.x;
    const int w    = tid >> 6;              // wave 0..7
    const int wv   = w & 3;                 // column tile
    const int kh   = w >> 2;                // K-half
    const int lane = tid & 63;
    const int r    = lane & 15;             // element-within-block
    const int q    = lane >> 4;             // k-octet selector
    const int el   = (blockIdx.x << 4) + r;

    // h1hi/h1lo: [16 el][64 units] shorts; 16B slots (8 units) XOR-swizzled
    // by (el&7). Slot s holds units 8s..8s+7; writer wave w owns slot w.
    __shared__ __align__(16) short h1hi[1024];
    __shared__ __align__(16) short h1lo[1024];
    __shared__ __align__(16) float pacc[1024];  // [8 w][64 lane][2] f32
    __shared__ __align__(16) float psum[512];   // [8 w][16 el][4] f32
    __shared__ __align__(16) float cs_lds[64];  // [16 el][4]

    // ---- one-time weight preload ----
    // layer-1 units for this lane: j = w*8 + q*2 + {0,1}
    float w1r[4][2], b1r[2];
    {
        const int j0 = (w << 3) + (q << 1);
        #pragma unroll
        for (int u = 0; u < 2; ++u) {
            const int j = j0 + u;
            b1r[u]   = b1[j];
            w1r[0][u] = W1[j];
            w1r[1][u] = W1[64 + j];
            w1r[2][u] = W1[128 + j];
            w1r[3][u] = W1[192 + j];
        }
    }
    // W2^T A-fragment, this wave's K-half only:
    // lane(q,r) holds A[m=r][k = kh*32 + q*8 + t] = W2[k][16wv + r]
    const int col = (wv << 4) + r;
    bf16x8 Wh, Wl;
    #pragma unroll
    for (int t = 0; t < 8; ++t) {
        const int k = (kh << 5) + (q << 3) + t;
        const float wgt = W2[(k << 6) + col];
        const short hi = f2bf_trunc(wgt);
        Wh[t] = hi;
        Wl[t] = f2bf_rne(wgt - bf2f(hi));
    }
    // bias enters only the kh=0 partial (added once to the combined sum)
    float b2i[4];
    #pragma unroll
    for (int reg = 0; reg < 4; ++reg)
        b2i[reg] = (kh == 0) ? b2[(wv << 4) + (q << 2) + reg] : 0.0f;
    // this wave finishes h2 rows c = 16wv + 4q + 2kh + {0,1}
    float w3r[2][3];
    #pragma unroll
    for (int u = 0; u < 2; ++u) {
        const int c = (wv << 4) + (q << 2) + (kh << 1) + u;
        w3r[u][0] = W3[c * 3 + 0];
        w3r[u][1] = W3[c * 3 + 1];
        w3r[u][2] = W3[c * 3 + 2];
    }
    const float b3v0 = b3[0], b3v1 = b3[1], b3v2 = b3[2];

    // ---- LDS addresses (element indices), hoisted ----
    const int widx  = (r << 6) + ((w ^ (r & 7)) << 3) + (q << 1);       // shorts
    const int ridx  = (r << 6) + ((((kh << 2) | q) ^ (r & 7)) << 3);    // shorts
    const int paw   = (w << 7) + (lane << 1);                           // floats
    const int wp    = ((1 - kh) << 2) | wv;                             // partner wave
    const int par   = (wp << 7) + (lane << 1);                          // floats
    const int pswidx = (w << 6) + (r << 2);                             // floats

    // ---- state ----
    float yb0 = init_state[el * 3 + 0];
    float yb1 = init_state[el * 3 + 1];
    float yb2 = init_state[el * 3 + 2];
    float cs0 = yb0, cs1 = yb1, cs2 = yb2;
    float ka0 = 0.f, ka1 = 0.f, ka2 = 0.f;

    if (w == 0 && q == 0) {
        out[(size_t)el * 3 + 0] = yb0;
        out[(size_t)el * 3 + 1] = yb1;
        out[(size_t)el * 3 + 2] = yb2;
    }

    const float* excp = exc + (size_t)el * T_SZ;
    float excB = excp[0];                   // k2..k4 column for step 0
    float excA = excB;                      // k1 column (clipped idx at step 0)
    float tA = tspan[0], tB = tspan[1];

    #pragma unroll 1
    for (int i = 0; i < T_SZ - 1; ++i) {
        const float excN = excp[(i < T_SZ - 2) ? (i + 1) : (T_SZ - 2)];
        const float tN   = tspan[(i <= T_SZ - 3) ? (i + 2) : (T_SZ - 1)];
        const float dt  = tB - tA;
        const float hdt = 0.5f * dt;

        #pragma unroll
        for (int ev = 0; ev < 4; ++ev) {
            const float excv = (ev == 0) ? excA : excB;
            const float s0 = cs0, s1 = cs1, s2 = cs2;

            // ---- layer 1: this wave's 2 units for element r ----
            {
                float hv[2];
                #pragma unroll
                for (int u = 0; u < 2; ++u) {
                    float pre = b1r[u];
                    pre = fmaf(s0,   w1r[0][u], pre);
                    pre = fmaf(s1,   w1r[1][u], pre);
                    pre = fmaf(s2,   w1r[2][u], pre);
                    pre = fmaf(excv, w1r[3][u], pre);
                    hv[u] = fast_tanh(pre);
                }
                const unsigned short h0 = (unsigned short)f2bf_trunc(hv[0]);
                const unsigned short h1_ = (unsigned short)f2bf_trunc(hv[1]);
                const uint32_t hi01 = (uint32_t)h0 | ((uint32_t)h1_ << 16);
                const unsigned short l0 = (unsigned short)f2bf_rne(hv[0] - bf2f((short)h0));
                const unsigned short l1 = (unsigned short)f2bf_rne(hv[1] - bf2f((short)h1_));
                const uint32_t lo01 = (uint32_t)l0 | ((uint32_t)l1 << 16);
                *reinterpret_cast<uint32_t*>(&h1hi[widx]) = hi01;
                *reinterpret_cast<uint32_t*>(&h1lo[widx]) = lo01;
            }
            __syncthreads();                              // bar1: h1 ready

            // ---- layer 2 partial: this wave's tile x K-half (3 MFMAs) ----
            const bf16x8 Hh = *reinterpret_cast<const bf16x8*>(&h1hi[ridx]);
            const bf16x8 Hl = *reinterpret_cast<const bf16x8*>(&h1lo[ridx]);
            f32x4 acc = {b2i[0], b2i[1], b2i[2], b2i[3]};
            acc = __builtin_amdgcn_mfma_f32_16x16x32_bf16(Wh, Hl, acc, 0, 0, 0);
            acc = __builtin_amdgcn_mfma_f32_16x16x32_bf16(Wl, Hh, acc, 0, 0, 0);
            acc = __builtin_amdgcn_mfma_f32_16x16x32_bf16(Wh, Hh, acc, 0, 0, 0);

            // exchange: write the float2 the PARTNER needs (its reg pair)
            const float wr0 = kh ? acc[0] : acc[2];
            const float wr1 = kh ? acc[1] : acc[3];
            *reinterpret_cast<float2*>(&pacc[paw]) = make_float2(wr0, wr1);
            __syncthreads();                              // bar2: pacc ready

            // own reg pair + partner's matching partial -> full h2 rows
            const float2 pr = *reinterpret_cast<const float2*>(&pacc[par]);
            const float own0 = kh ? acc[2] : acc[0];
            const float own1 = kh ? acc[3] : acc[1];
            const float h2a = fast_tanh(own0 + pr.x);
            const float h2b = fast_tanh(own1 + pr.y);

            float p0 = fmaf(h2b, w3r[1][0], h2a * w3r[0][0]);
            float p1 = fmaf(h2b, w3r[1][1], h2a * w3r[0][1]);
            float p2 = fmaf(h2b, w3r[1][2], h2a * w3r[0][2]);
            // reduce over the 4 q-groups
            p0 += __shfl_xor(p0, 16, 64);
            p1 += __shfl_xor(p1, 16, 64);
            p2 += __shfl_xor(p2, 16, 64);
            p0 += __shfl_xor(p0, 32, 64);
            p1 += __shfl_xor(p1, 32, 64);
            p2 += __shfl_xor(p2, 32, 64);
            if (q == 0) {
                *reinterpret_cast<f32x4*>(&psum[pswidx]) = (f32x4){p0, p1, p2, p2};
            }
            __syncthreads();                              // bar3: psum ready

            // ---- wave 0 only: combine 8 partials + nn + physics + RK4 ----
            if (w == 0) {
                // lane(q,r) reads partial regions 2q and 2q+1, shfl-combines q
                const f32x4 va = *reinterpret_cast<const f32x4*>(&psum[(q << 7) + (r << 2)]);
                const f32x4 vb = *reinterpret_cast<const f32x4*>(&psum[(q << 7) + 64 + (r << 2)]);
                float S0 = va[0] + vb[0];
                float S1 = va[1] + vb[1];
                float S2 = va[2] + vb[2];
                S0 += __shfl_xor(S0, 16, 64);
                S1 += __shfl_xor(S1, 16, 64);
                S2 += __shfl_xor(S2, 16, 64);
                S0 += __shfl_xor(S0, 32, 64);
                S1 += __shfl_xor(S1, 32, 64);
                S2 += __shfl_xor(S2, 32, 64);

                const float nn0 = C_NN_SCALE * fast_tanh(S0 + b3v0);
                const float nn1 = C_NN_SCALE * fast_tanh(S1 + b3v1);
                const float nn2 = C_NN_SCALE * fast_tanh(S2 + b3v2);

                const float lM  = clampf(s0, C_LMIN, C_LMAX);
                const float act = clampf(s1, 0.01f, 1.0f);
                const float fat = clampf(s2, 0.0f, 1.0f);
                const float a_eff = act * (1.0f - fat);
                const float sin_p = fminf(C_L0SIN * fast_rcp(lM), 0.99f);
                const float cp2   = fmaf(-sin_p, sin_p, 1.0f);
                const float inv_cp = fast_rsq(cp2);
                const float cos_p  = cp2 * inv_cp;
                const float lT   = C_LMT_DEF - lM * cos_p;
                const float epsT = (lT - C_LTS) * C_INV_LTS;
                const float fT   = (epsT > 0.0f) ? C_CT * (__expf(C_KT * epsT) - 1.0f) : 0.0f;
                const float lN   = lM * C_INV_L0;
                const float d1   = lN - 1.0f;
                const float fL   = __expf(-d1 * d1 * (1.0f / 0.45f));
                const float fPE  = (lN > 1.0f) ? (__expf(8.3333333333f * d1) - 1.0f) * C_INV_EM5 : 0.0f;
                const float fV   = (fT * inv_cp - fPE) * fast_rcp(fmaf(a_eff, fL, 0.001f));
                float vN = (fV - 1.0f) * fast_rcp(fmaf(fabsf(fV), C_AF_INV, 1.0f));
                vN = clampf(vN, -1.0f, 1.5f);
                const float r0v = fmaf(C_VMAX_L0, vN, nn0);
                const float g15 = fmaf(1.5f, act, 0.5f);
                const float inv_tau = (excv > act) ? fast_rcp(C_TAU_ACT * g15)
                                                   : g15 * (1.0f / C_TAU_DEACT);
                const float r1v = fmaf(excv - act, inv_tau, nn1);
                const float r2v = C_FAT_RATE * a_eff * (1.0f - fat)
                                - C_REC_RATE * (1.0f - a_eff) * fat + nn2;

                float ns0, ns1, ns2;
                if (ev == 0) {
                    ka0 = r0v; ka1 = r1v; ka2 = r2v;
                    ns0 = fmaf(hdt, r0v, yb0); ns1 = fmaf(hdt, r1v, yb1); ns2 = fmaf(hdt, r2v, yb2);
                } else if (ev == 1) {
                    ka0 = fmaf(2.0f, r0v, ka0); ka1 = fmaf(2.0f, r1v, ka1); ka2 = fmaf(2.0f, r2v, ka2);
                    ns0 = fmaf(hdt, r0v, yb0); ns1 = fmaf(hdt, r1v, yb1); ns2 = fmaf(hdt, r2v, yb2);
                } else if (ev == 2) {
                    ka0 = fmaf(2.0f, r0v, ka0); ka1 = fmaf(2.0f, r1v, ka1); ka2 = fmaf(2.0f, r2v, ka2);
                    ns0 = fmaf(dt, r0v, yb0); ns1 = fmaf(dt, r1v, yb1); ns2 = fmaf(dt, r2v, yb2);
                } else {
                    const float c6 = dt * (1.0f / 6.0f);
                    yb0 = fmaf(c6, ka0 + r0v, yb0);
                    yb1 = fmaf(c6, ka1 + r1v, yb1);
                    yb2 = fmaf(c6, ka2 + r2v, yb2);
                    ns0 = yb0; ns1 = yb1; ns2 = yb2;
                }
                if (q == 0) {
                    *reinterpret_cast<f32x4*>(&cs_lds[r << 2]) = (f32x4){ns0, ns1, ns2, 0.f};
                    if (ev == 3) {
                        const size_t ob = (size_t)(i + 1) * (B_SZ * 3) + (size_t)el * 3;
                        out[ob + 0] = ns0; out[ob + 1] = ns1; out[ob + 2] = ns2;
                    }
                }
            }
            __syncthreads();                              // bar4: cs published

            // everyone (incl. wave 0) takes the q==0-published state
            {
                const f32x4 c = *reinterpret_cast<const f32x4*>(&cs_lds[r << 2]);
                cs0 = c[0]; cs1 = c[1]; cs2 = c[2];
            }
        }

        excA = excB; excB = excN; tA = tB; tB = tN;
    }
}

extern "C" void kernel_launch(void* const* d_in, const int* in_sizes, int n_in,
                              void* d_out, int out_size, void* d_ws, size_t ws_size,
                              hipStream_t stream) {
    const float* init  = (const float*)d_in[0];
    const float* exc   = (const float*)d_in[1];
    const float* tspan = (const float*)d_in[2];
    const float* W1    = (const float*)d_in[3];
    const float* b1    = (const float*)d_in[4];
    const float* W2    = (const float*)d_in[5];
    const float* b2    = (const float*)d_in[6];
    const float* W3    = (const float*)d_in[7];
    const float* b3    = (const float*)d_in[8];

    hipLaunchKernelGGL(ode_kernel, dim3(B_SZ / 16), dim3(512), 0, stream,
                       init, exc, tspan, W1, b1, W2, b2, W3, b3, (float*)d_out);
}

// Round 5
// 10557.856 us; speedup vs baseline: 1.0152x; 1.0152x over previous
//
#include <hip/hip_runtime.h>
#include <cstdint>

#define B_SZ 8192
#define T_SZ 2048

// ---- model constants ----
#define C_LTS       0.126f
#define C_LMIN      (0.5f * 0.089f)
#define C_LMAX      (1.6f * 0.089f)
#define C_KT        35.0f
#define C_CT        0.2f
#define C_VMAX_L0   (10.0f * 0.089f)
#define C_AF_INV    4.0f
#define C_FAT_RATE  0.01f
#define C_REC_RATE  0.002f
#define C_TAU_ACT   0.01f
#define C_TAU_DEACT 0.04f
#define C_L0SIN     0.0077598346f          // L0 * sin(0.0873)
#define C_LMT_DEF   0.2146610680f          // LTS + L0*cos(0.0873)
#define C_INV_EM5   0.006783655f           // 1/(e^5 - 1)
#define C_INV_LTS   (1.0f / 0.126f)
#define C_INV_L0    (1.0f / 0.089f)
#define C_NN_SCALE  0.02f                  // (1-PHYSICS_WEIGHT) * 0.1

typedef __attribute__((ext_vector_type(8))) short bf16x8;
typedef __attribute__((ext_vector_type(4))) float f32x4;

__device__ __forceinline__ float fast_rcp(float x) { return __builtin_amdgcn_rcpf(x); }
__device__ __forceinline__ float fast_rsq(float x) { return __builtin_amdgcn_rsqf(x); }
__device__ __forceinline__ float fast_tanh(float x) {
    const float e2 = __expf(2.0f * x);
    return 1.0f - 2.0f * fast_rcp(e2 + 1.0f);
}
__device__ __forceinline__ float clampf(float x, float lo, float hi) {
    return fminf(fmaxf(x, lo), hi);
}
__device__ __forceinline__ short f2bf_trunc(float f) {
    return (short)(__float_as_uint(f) >> 16);
}
__device__ __forceinline__ short f2bf_rne(float f) {
    uint32_t u = __float_as_uint(f);
    u += 0x7fff + ((u >> 16) & 1);
    return (short)(u >> 16);
}
__device__ __forceinline__ float bf2f(short s) {
    return __uint_as_float(((uint32_t)(unsigned short)s) << 16);
}

// 4 waves (256 threads) per block cooperating on TWO independent 16-element
// groups (32 elements). 256 blocks = 1 block/CU (1 wave/SIMD).
// Rationale (R4 post-mortem): adding waves per group grows cooperation
// overhead; instead amortize ONE barrier skeleton over 2 groups and let the
// second group's independent instructions fill the first group's latency
// (MFMA chains, LDS round-trips, exp chains). Weights are shared.
// Per stage: layer1(g0,g1) -> bar1 -> MFMA(g0,g1) -> reduce(g0,g1) ->
// psum write -> bar2 -> per-lane tail for group gt=q&1 -> cs swap via
// shfl_xor(16). 2 barriers/stage, no cs LDS round-trip.
// Per-group arithmetic bit-identical to the round-2/3 kernels.
__global__ __launch_bounds__(256) void ode_kernel(
    const float* __restrict__ init_state,   // (B,3)
    const float* __restrict__ exc,          // (B,T)
    const float* __restrict__ tspan,        // (T,)
    const float* __restrict__ W1,           // (4,64)
    const float* __restrict__ b1,           // (64,)
    const float* __restrict__ W2,           // (64,64)
    const float* __restrict__ b2,           // (64,)
    const float* __restrict__ W3,           // (64,3)
    const float* __restrict__ b3,           // (3,)
    float* __restrict__ out)                // (T,B,3)
{
    const int tid  = threadIdx.x;
    const int wv   = tid >> 6;              // wave 0..3 = column tile
    const int lane = tid & 63;
    const int r    = lane & 15;             // element-within-group
    const int q    = lane >> 4;             // k-octet selector
    const int gt   = q & 1;                 // tail group handled by this lane
    const int el0  = (blockIdx.x << 5) + r; // group-0 element
    const int el1  = el0 + 16;              // group-1 element
    const int el_t = el0 + (gt << 4);       // tail element

    // per group: [16 el][64 units] shorts, 16B slots XOR-swizzled by (el&7)
    __shared__ __align__(16) short h1hi[2048];
    __shared__ __align__(16) short h1lo[2048];
    __shared__ __align__(16) float psum[512];   // [2 g][4 wv][16 el][4] f32

    // ---- one-time weight preload (shared across both groups) ----
    float w1r[4][4], b1r[4];
    {
        const int j0 = (wv << 4) + (q << 2);
        #pragma unroll
        for (int u = 0; u < 4; ++u) {
            const int j = j0 + u;
            b1r[u]   = b1[j];
            w1r[0][u] = W1[j];
            w1r[1][u] = W1[64 + j];
            w1r[2][u] = W1[128 + j];
            w1r[3][u] = W1[192 + j];
        }
    }
    // W2^T A-fragments: lane(q,r) holds A[m=r][k = ks*32 + q*8 + t]
    const int col = (wv << 4) + r;
    bf16x8 Wh[2], Wl[2];
    #pragma unroll
    for (int ks = 0; ks < 2; ++ks)
        #pragma unroll
        for (int t = 0; t < 8; ++t) {
            const int k = (ks << 5) + (q << 3) + t;
            const float wgt = W2[(k << 6) + col];
            const short hi = f2bf_trunc(wgt);
            Wh[ks][t] = hi;
            Wl[ks][t] = f2bf_rne(wgt - bf2f(hi));
        }
    // per-lane D rows: c = 16wv + 4q + reg
    float b2v4[4], w3r[4][3];
    #pragma unroll
    for (int reg = 0; reg < 4; ++reg) {
        const int c = (wv << 4) + (q << 2) + reg;
        b2v4[reg]  = b2[c];
        w3r[reg][0] = W3[c * 3 + 0];
        w3r[reg][1] = W3[c * 3 + 1];
        w3r[reg][2] = W3[c * 3 + 2];
    }
    const float b3v0 = b3[0], b3v1 = b3[1], b3v2 = b3[2];

    // ---- LDS addresses (element indices), hoisted ----
    const int slotW = (wv << 1) + (q >> 1);
    const int widx  = (r << 6) + ((slotW ^ (r & 7)) << 3) + ((q & 1) << 2);
    const int ridx0 = (r << 6) + ((q       ^ (r & 7)) << 3);
    const int ridx1 = (r << 6) + (((4 | q) ^ (r & 7)) << 3);
    const int pswidx = (wv << 6) + (r << 2);          // + (g<<8); q==0 writers
    const int prd    = (gt << 8) + (r << 2);          // tail psum base

    // ---- state: cs for BOTH groups on every lane; yb/ka for group gt ----
    float cs0_0 = init_state[el0 * 3 + 0];
    float cs0_1 = init_state[el0 * 3 + 1];
    float cs0_2 = init_state[el0 * 3 + 2];
    float cs1_0 = init_state[el1 * 3 + 0];
    float cs1_1 = init_state[el1 * 3 + 1];
    float cs1_2 = init_state[el1 * 3 + 2];
    float yb0 = gt ? cs1_0 : cs0_0;
    float yb1 = gt ? cs1_1 : cs0_1;
    float yb2 = gt ? cs1_2 : cs0_2;
    float ka0 = 0.f, ka1 = 0.f, ka2 = 0.f;

    if (wv == 0 && q < 2) {
        const size_t ob = (size_t)el_t * 3;
        out[ob + 0] = yb0; out[ob + 1] = yb1; out[ob + 2] = yb2;
    }

    const float* excp0 = exc + (size_t)el0 * T_SZ;
    const float* excp1 = exc + (size_t)el1 * T_SZ;
    float excB0 = excp0[0], excB1 = excp1[0];
    float excA0 = excB0,    excA1 = excB1;
    float tA = tspan[0], tB = tspan[1];

    #pragma unroll 1
    for (int i = 0; i < T_SZ - 1; ++i) {
        const int ip = (i < T_SZ - 2) ? (i + 1) : (T_SZ - 2);
        const float excN0 = excp0[ip];
        const float excN1 = excp1[ip];
        const float tN    = tspan[(i <= T_SZ - 3) ? (i + 2) : (T_SZ - 1)];
        const float dt  = tB - tA;
        const float hdt = 0.5f * dt;

        #pragma unroll 1
        for (int ev = 0; ev < 4; ++ev) {
            const float excv0 = (ev == 0) ? excA0 : excB0;
            const float excv1 = (ev == 0) ? excA1 : excB1;

            // ---- layer 1: 4 units x 2 groups for element r ----
            #pragma unroll
            for (int g = 0; g < 2; ++g) {
                const float s0 = g ? cs1_0 : cs0_0;
                const float s1 = g ? cs1_1 : cs0_1;
                const float s2 = g ? cs1_2 : cs0_2;
                const float ex = g ? excv1 : excv0;
                float hv[4];
                #pragma unroll
                for (int u = 0; u < 4; ++u) {
                    float pre = b1r[u];
                    pre = fmaf(s0, w1r[0][u], pre);
                    pre = fmaf(s1, w1r[1][u], pre);
                    pre = fmaf(s2, w1r[2][u], pre);
                    pre = fmaf(ex, w1r[3][u], pre);
                    hv[u] = fast_tanh(pre);
                }
                const unsigned short h0 = (unsigned short)f2bf_trunc(hv[0]);
                const unsigned short h1_ = (unsigned short)f2bf_trunc(hv[1]);
                const unsigned short h2_ = (unsigned short)f2bf_trunc(hv[2]);
                const unsigned short h3_ = (unsigned short)f2bf_trunc(hv[3]);
                const uint32_t hi01 = (uint32_t)h0 | ((uint32_t)h1_ << 16);
                const uint32_t hi23 = (uint32_t)h2_ | ((uint32_t)h3_ << 16);
                const unsigned short l0 = (unsigned short)f2bf_rne(hv[0] - bf2f((short)h0));
                const unsigned short l1 = (unsigned short)f2bf_rne(hv[1] - bf2f((short)h1_));
                const unsigned short l2 = (unsigned short)f2bf_rne(hv[2] - bf2f((short)h2_));
                const unsigned short l3 = (unsigned short)f2bf_rne(hv[3] - bf2f((short)h3_));
                const uint32_t lo01 = (uint32_t)l0 | ((uint32_t)l1 << 16);
                const uint32_t lo23 = (uint32_t)l2 | ((uint32_t)l3 << 16);
                const int o = g << 10;
                *reinterpret_cast<uint2*>(&h1hi[widx + o]) = make_uint2(hi01, hi23);
                *reinterpret_cast<uint2*>(&h1lo[widx + o]) = make_uint2(lo01, lo23);
            }
            __syncthreads();                              // bar1: h1 ready

            // ---- layer 2 (transposed), both groups: 12 MFMAs, 4 chains ----
            f32x4 accA[2], accB[2];
            #pragma unroll
            for (int g = 0; g < 2; ++g) {
                const int o = g << 10;
                const bf16x8 Hh0 = *reinterpret_cast<const bf16x8*>(&h1hi[ridx0 + o]);
                const bf16x8 Hh1 = *reinterpret_cast<const bf16x8*>(&h1hi[ridx1 + o]);
                const bf16x8 Hl0 = *reinterpret_cast<const bf16x8*>(&h1lo[ridx0 + o]);
                const bf16x8 Hl1 = *reinterpret_cast<const bf16x8*>(&h1lo[ridx1 + o]);
                accA[g] = (f32x4){b2v4[0], b2v4[1], b2v4[2], b2v4[3]};
                accB[g] = (f32x4){0.f, 0.f, 0.f, 0.f};
                accA[g] = __builtin_amdgcn_mfma_f32_16x16x32_bf16(Wh[0], Hl0, accA[g], 0, 0, 0);
                accB[g] = __builtin_amdgcn_mfma_f32_16x16x32_bf16(Wh[1], Hl1, accB[g], 0, 0, 0);
                accA[g] = __builtin_amdgcn_mfma_f32_16x16x32_bf16(Wl[0], Hh0, accA[g], 0, 0, 0);
                accB[g] = __builtin_amdgcn_mfma_f32_16x16x32_bf16(Wl[1], Hh1, accB[g], 0, 0, 0);
                accA[g] = __builtin_amdgcn_mfma_f32_16x16x32_bf16(Wh[0], Hh0, accA[g], 0, 0, 0);
                accB[g] = __builtin_amdgcn_mfma_f32_16x16x32_bf16(Wh[1], Hh1, accB[g], 0, 0, 0);
            }

            // ---- tanh + layer-3 partials + q-reduce, both groups ----
            #pragma unroll
            for (int g = 0; g < 2; ++g) {
                float p0 = 0.f, p1 = 0.f, p2 = 0.f;
                #pragma unroll
                for (int reg = 0; reg < 4; ++reg) {
                    const float h2v = fast_tanh(accA[g][reg] + accB[g][reg]);
                    p0 = fmaf(h2v, w3r[reg][0], p0);
                    p1 = fmaf(h2v, w3r[reg][1], p1);
                    p2 = fmaf(h2v, w3r[reg][2], p2);
                }
                p0 += __shfl_xor(p0, 16, 64);
                p1 += __shfl_xor(p1, 16, 64);
                p2 += __shfl_xor(p2, 16, 64);
                p0 += __shfl_xor(p0, 32, 64);
                p1 += __shfl_xor(p1, 32, 64);
                p2 += __shfl_xor(p2, 32, 64);
                if (q == 0) {
                    *reinterpret_cast<f32x4*>(&psum[(g << 8) + pswidx]) =
                        (f32x4){p0, p1, p2, p2};
                }
            }
            __syncthreads();                              // bar2: psum ready

            // ---- per-lane tail: group gt, element r ----
            const f32x4 v0 = *reinterpret_cast<const f32x4*>(&psum[prd]);
            const f32x4 v1 = *reinterpret_cast<const f32x4*>(&psum[prd + 64]);
            const f32x4 v2 = *reinterpret_cast<const f32x4*>(&psum[prd + 128]);
            const f32x4 v3 = *reinterpret_cast<const f32x4*>(&psum[prd + 192]);
            const float S0 = (v0[0] + v1[0]) + (v2[0] + v3[0]);
            const float S1 = (v0[1] + v1[1]) + (v2[1] + v3[1]);
            const float S2 = (v0[2] + v1[2]) + (v2[2] + v3[2]);

            const float nn0 = C_NN_SCALE * fast_tanh(S0 + b3v0);
            const float nn1 = C_NN_SCALE * fast_tanh(S1 + b3v1);
            const float nn2 = C_NN_SCALE * fast_tanh(S2 + b3v2);

            const float ts0 = gt ? cs1_0 : cs0_0;         // stage-input state
            const float ts1 = gt ? cs1_1 : cs0_1;
            const float ts2 = gt ? cs1_2 : cs0_2;
            const float tex = gt ? excv1 : excv0;

            const float lM  = clampf(ts0, C_LMIN, C_LMAX);
            const float act = clampf(ts1, 0.01f, 1.0f);
            const float fat = clampf(ts2, 0.0f, 1.0f);
            const float a_eff = act * (1.0f - fat);
            const float sin_p = fminf(C_L0SIN * fast_rcp(lM), 0.99f);
            const float cp2   = fmaf(-sin_p, sin_p, 1.0f);
            const float inv_cp = fast_rsq(cp2);
            const float cos_p  = cp2 * inv_cp;
            const float lT   = C_LMT_DEF - lM * cos_p;
            const float epsT = (lT - C_LTS) * C_INV_LTS;
            const float fT   = (epsT > 0.0f) ? C_CT * (__expf(C_KT * epsT) - 1.0f) : 0.0f;
            const float lN   = lM * C_INV_L0;
            const float d1   = lN - 1.0f;
            const float fL   = __expf(-d1 * d1 * (1.0f / 0.45f));
            const float fPE  = (lN > 1.0f) ? (__expf(8.3333333333f * d1) - 1.0f) * C_INV_EM5 : 0.0f;
            const float fV   = (fT * inv_cp - fPE) * fast_rcp(fmaf(a_eff, fL, 0.001f));
            float vN = (fV - 1.0f) * fast_rcp(fmaf(fabsf(fV), C_AF_INV, 1.0f));
            vN = clampf(vN, -1.0f, 1.5f);
            const float r0v = fmaf(C_VMAX_L0, vN, nn0);
            const float g15 = fmaf(1.5f, act, 0.5f);
            const float inv_tau = (tex > act) ? fast_rcp(C_TAU_ACT * g15)
                                              : g15 * (1.0f / C_TAU_DEACT);
            const float r1v = fmaf(tex - act, inv_tau, nn1);
            const float r2v = C_FAT_RATE * a_eff * (1.0f - fat)
                            - C_REC_RATE * (1.0f - a_eff) * fat + nn2;

            // ---- RK4 bookkeeping for group gt ----
            float ns0, ns1, ns2;
            if (ev == 0) {
                ka0 = r0v; ka1 = r1v; ka2 = r2v;
                ns0 = fmaf(hdt, r0v, yb0); ns1 = fmaf(hdt, r1v, yb1); ns2 = fmaf(hdt, r2v, yb2);
            } else if (ev == 1) {
                ka0 = fmaf(2.0f, r0v, ka0); ka1 = fmaf(2.0f, r1v, ka1); ka2 = fmaf(2.0f, r2v, ka2);
                ns0 = fmaf(hdt, r0v, yb0); ns1 = fmaf(hdt, r1v, yb1); ns2 = fmaf(hdt, r2v, yb2);
            } else if (ev == 2) {
                ka0 = fmaf(2.0f, r0v, ka0); ka1 = fmaf(2.0f, r1v, ka1); ka2 = fmaf(2.0f, r2v, ka2);
                ns0 = fmaf(dt, r0v, yb0); ns1 = fmaf(dt, r1v, yb1); ns2 = fmaf(dt, r2v, yb2);
            } else {
                const float c6 = dt * (1.0f / 6.0f);
                yb0 = fmaf(c6, ka0 + r0v, yb0);
                yb1 = fmaf(c6, ka1 + r1v, yb1);
                yb2 = fmaf(c6, ka2 + r2v, yb2);
                ns0 = yb0; ns1 = yb1; ns2 = yb2;
                if (wv == 0 && q < 2) {
                    const size_t ob = (size_t)(i + 1) * (B_SZ * 3) + (size_t)el_t * 3;
                    out[ob + 0] = ns0; out[ob + 1] = ns1; out[ob + 2] = ns2;
                }
            }

            // ---- publish new state to both q-parities via lane swap ----
            const float sw0 = __shfl_xor(ns0, 16, 64);
            const float sw1 = __shfl_xor(ns1, 16, 64);
            const float sw2 = __shfl_xor(ns2, 16, 64);
            cs0_0 = gt ? sw0 : ns0;  cs1_0 = gt ? ns0 : sw0;
            cs0_1 = gt ? sw1 : ns1;  cs1_1 = gt ? ns1 : sw1;
            cs0_2 = gt ? sw2 : ns2;  cs1_2 = gt ? ns2 : sw2;
        }

        excA0 = excB0; excB0 = excN0;
        excA1 = excB1; excB1 = excN1;
        tA = tB; tB = tN;
    }
}

extern "C" void kernel_launch(void* const* d_in, const int* in_sizes, int n_in,
                              void* d_out, int out_size, void* d_ws, size_t ws_size,
                              hipStream_t stream) {
    const float* init  = (const float*)d_in[0];
    const float* exc   = (const float*)d_in[1];
    const float* tspan = (const float*)d_in[2];
    const float* W1    = (const float*)d_in[3];
    const float* b1    = (const float*)d_in[4];
    const float* W2    = (const float*)d_in[5];
    const float* b2    = (const float*)d_in[6];
    const float* W3    = (const float*)d_in[7];
    const float* b3    = (const float*)d_in[8];

    hipLaunchKernelGGL(ode_kernel, dim3(B_SZ / 32), dim3(256), 0, stream,
                       init, exc, tspan, W1, b1, W2, b2, W3, b3, (float*)d_out);
}